// Round 7
// baseline (16802.336 us; speedup 1.0000x reference)
//
#include <hip/hip_runtime.h>
#include <hip/hip_fp16.h>
#include <math.h>
#include <stdint.h>

// MobiusGRU T=256 B=64 D=H=512, 2 layers.
// R14 = FUSED two-layer scan. One 256-WG kernel runs layer-1 step t and
// layer-2 step t-1 per iteration; x for layer-2 IS the freshly gathered h1
// (same LDS, zero cross-layer comm). Layer-2's Ux comes from in-scan f16 dots
// vs Wih2 (same verified phase-A/B pattern) + one 3-scalar norm round.
// Layer-2's exchange rounds are scheduled into layer-1's flight windows.
// Prep = layer-1 only (ih transpose + GEMM + nonlin) + 3x weight repack.
// Comm fabric unchanged from R7 (verified): fence-free tagged {tag,value}
// u64 relaxed agent atomics, monotone tags, narrow rounds packed per layer
// into one [64][4][32] array (slots: L1 S1=0..9,S3=10..17,S4=18..20;
// L2 ihN=0..2,S1=3..12,S3=13..20,S4=21..23).

#define T_  256
#define B_  64
#define H_  512
#define G3_ 1536
#define EPSF 1e-15f
#define CLIPF (1.0f - 1e-5f)
#define SCOPE_AGENT __HIP_MEMORY_SCOPE_AGENT

typedef _Float16 v2h __attribute__((ext_vector_type(2)));

__device__ __forceinline__ float fdot2_(unsigned int w, unsigned int h, float c){
#if __has_builtin(__builtin_amdgcn_fdot2)
  return __builtin_amdgcn_fdot2(__builtin_bit_cast(v2h, w), __builtin_bit_cast(v2h, h), c, false);
#else
  const __half2 wh = __builtin_bit_cast(__half2, w);
  const __half2 hh = __builtin_bit_cast(__half2, h);
  return c + __low2float(wh)*__low2float(hh) + __high2float(wh)*__high2float(hh);
#endif
}

__device__ __forceinline__ float artanh_c(float x){
  x = fminf(fmaxf(x, -CLIPF), CLIPF);
  return 0.5f * logf((1.0f + x) / (1.0f - x));
}
__device__ __forceinline__ float sigmoidf_(float x){ return 1.0f/(1.0f+expf(-x)); }
__device__ __forceinline__ float hsum4(float4 v){ return (v.x+v.y)+(v.z+v.w); }
__device__ __forceinline__ float sum8(const float* r){
  const float4* p = (const float4*)r;
  return hsum4(p[0]) + hsum4(p[1]);
}

__device__ __forceinline__ void postf(unsigned long long* p, float x, unsigned tag){
  unsigned long long v = ((unsigned long long)tag << 32) |
                         (unsigned long long)__float_as_uint(x);
  __hip_atomic_store(p, v, __ATOMIC_RELAXED, SCOPE_AGENT);
}
__device__ __forceinline__ float pollf(const unsigned long long* p, unsigned tag){
  unsigned long long v = __hip_atomic_load(p, __ATOMIC_RELAXED, SCOPE_AGENT);
  while ((unsigned)(v >> 32) != tag)
    v = __hip_atomic_load(p, __ATOMIC_RELAXED, SCOPE_AGENT);
  return __uint_as_float((unsigned)v);
}

template<int NS>
__device__ __forceinline__ void wave_reduce_store(float (&v)[NS], float* red, int tid){
  #pragma unroll
  for (int off = 32; off > 0; off >>= 1)
    #pragma unroll
    for (int s = 0; s < NS; s++) v[s] += __shfl_xor(v[s], off);
  if ((tid & 63) == 0)
    #pragma unroll
    for (int s = 0; s < NS; s++) red[s*8 + (tid >> 6)] = v[s];
}

// verified (R10): full gate evaluation from stats
__device__ __forceinline__ float gate_val(float a, float y, float bv,
    float A2, float AY, float Y2, float AB, float YB, float B2,
    float xn, float art_h){
  const float mraw = sqrtf(A2);
  const float mnc = fmaxf(mraw, EPSF);
  const float alpha = (mraw <= EPSF) ? 0.f : (tanhf(mnc/xn*art_h)/mnc);
  const float X2 = alpha*alpha*A2, XY = alpha*AY, XB = alpha*AB;
  const float cA1 = 1.f + 2.f*XY + Y2, cB1 = 1.f - X2;
  const float den1 = fmaxf(1.f + 2.f*XY + X2*Y2, EPSF), id1 = 1.f/den1;
  const float T2 = fmaxf((cA1*cA1*X2 + 2.f*cA1*cB1*XY + cB1*cB1*Y2)*id1*id1, 0.f);
  const float TB = (cA1*XB + cB1*YB)*id1;
  const float cA2 = 1.f + 2.f*TB + B2, cB2 = 1.f - T2;
  const float den2 = fmaxf(1.f + 2.f*TB + T2*B2, EPSF), id2 = 1.f/den2;
  const float U2 = fmaxf((cA2*cA2*T2 + 2.f*cA2*cB2*TB + cB2*cB2*B2)*id2*id2, 0.f);
  const float un = fmaxf(sqrtf(U2), EPSF);
  const float lsc = artanh_c(un)/un;
  const float t1el = (cA1*(alpha*a) + cB1*y)*id1;
  const float uel  = (cA2*t1el + cB2*bv)*id2;
  return sigmoidf_(lsc*uel);
}

// ---- transpose weight_ih [1536][512] -> WihT [512][1536]
__global__ void k_prep_ih(const float* __restrict__ Wih, float* __restrict__ WihT){
  int i = blockIdx.x * blockDim.x + threadIdx.x;
  if (i >= H_ * G3_) return;
  int k = i / G3_, n = i % G3_;
  WihT[i] = Wih[n * H_ + k];
}

__device__ __forceinline__ uint4 pack8h(const float* s){
  __half2 p0 = __halves2half2(__float2half_rn(s[0]), __float2half_rn(s[1]));
  __half2 p1 = __halves2half2(__float2half_rn(s[2]), __float2half_rn(s[3]));
  __half2 p2 = __halves2half2(__float2half_rn(s[4]), __float2half_rn(s[5]));
  __half2 p3 = __halves2half2(__float2half_rn(s[6]), __float2half_rn(s[7]));
  uint4 r;
  r.x = __builtin_bit_cast(unsigned int, p0);
  r.y = __builtin_bit_cast(unsigned int, p1);
  r.z = __builtin_bit_cast(unsigned int, p2);
  r.w = __builtin_bit_cast(unsigned int, p3);
  return r;
}

// ---- [1536][512] weight -> col-split f16 layouts (z rows 1024+j, r rows j,
// c rows 512+j), as R7. Used for Whh1, Whh2 and Wih2.
__global__ void k_prep_hhR(const float* __restrict__ W, uint4* __restrict__ Dzr,
                           uint4* __restrict__ Dhc){
  int i = blockIdx.x * blockDim.x + threadIdx.x;   // 98304 total
  if (i < 65536){
    int w = i >> 14, rem = i & 16383;
    int ii = rem >> 9, tid = rem & 511;
    int c = tid & 255, ks = tid >> 8;
    int j = 128*w + (c & 127);
    int row = (c < 128) ? (1024 + j) : j;
    int k0 = ks*256 + ii*8;
    Dzr[i] = pack8h(W + row*H_ + k0);
  } else {
    int e = i - 65536;                              // 32768
    int w = e >> 13, rem = e & 8191;
    int q = rem >> 11, rem2 = rem & 2047;
    int ii = rem2 >> 7, c = rem2 & 127;
    int row = 512 + 128*w + c;
    int k0 = q*128 + ii*8;
    Dhc[e] = pack8h(W + row*H_ + k0);
  }
}

// ---- tiled f32 GEMM: C[16384][1536] = A[16384][512] * Bt[512][1536]
__global__ __launch_bounds__(256) void k_gemm(const float* __restrict__ A,
                                              const float* __restrict__ Bt,
                                              float* __restrict__ C){
  const int N = G3_, K = H_;
  const int mbase = blockIdx.x * 64, nbase = blockIdx.y * 64;
  __shared__ float As[32][65];
  __shared__ float Bs[32][65];
  const int tid = threadIdx.x;
  const int tm = tid >> 4, tn = tid & 15;
  float acc[4][4] = {};
  for (int k0 = 0; k0 < K; k0 += 32){
    #pragma unroll
    for (int i = 0; i < 8; i++){
      int e = tid + 256*i;
      int m = e >> 5, k = e & 31;
      As[k][m] = A[(size_t)(mbase + m) * K + k0 + k];
      int kk = e >> 6, n = e & 63;
      Bs[kk][n] = Bt[(size_t)(k0 + kk) * N + nbase + n];
    }
    __syncthreads();
    #pragma unroll
    for (int kk = 0; kk < 32; kk++){
      float av[4], bv[4];
      #pragma unroll
      for (int i = 0; i < 4; i++) av[i] = As[kk][tm*4+i];
      #pragma unroll
      for (int j = 0; j < 4; j++) bv[j] = Bs[kk][tn*4+j];
      #pragma unroll
      for (int i = 0; i < 4; i++)
        #pragma unroll
        for (int j = 0; j < 4; j++)
          acc[i][j] = fmaf(av[i], bv[j], acc[i][j]);
    }
    __syncthreads();
  }
  #pragma unroll
  for (int i = 0; i < 4; i++)
    #pragma unroll
    for (int j = 0; j < 4; j++)
      C[(size_t)(mbase + tm*4 + i) * N + nbase + tn*4 + j] = acc[i][j];
}

// ---- mobius_matvec tail on Ux rows (layer 1 only)
__global__ void k_nonlin(const float* __restrict__ X, float* __restrict__ D){
  const int row = blockIdx.x;
  const int lane = threadIdx.x;
  const float* x = X + (size_t)row * H_;
  float s = 0.0f;
  for (int k = lane; k < H_; k += 64){ float v = x[k]; s = fmaf(v, v, s); }
  #pragma unroll
  for (int off = 32; off > 0; off >>= 1) s += __shfl_xor(s, off);
  const float xn = fmaxf(sqrtf(s), EPSF);
  const float art = artanh_c(xn);
  float* drow = D + (size_t)row * G3_;
  for (int g = 0; g < 3; g++){
    float* mx = drow + g * H_;
    float s2 = 0.0f;
    for (int k = lane; k < H_; k += 64){ float v = mx[k]; s2 = fmaf(v, v, s2); }
    #pragma unroll
    for (int off = 32; off > 0; off >>= 1) s2 += __shfl_xor(s2, off);
    const float raw = sqrtf(s2);
    const float mn = fmaxf(raw, EPSF);
    const float scale = (raw <= EPSF) ? 0.0f : (tanhf(mn / xn * art) / mn);
    for (int k = lane; k < H_; k += 64) mx[k] *= scale;
  }
}

// ---- fused scan: 4 WGs/row, layer-1 step t + layer-2 step t-1 per iteration
__global__ __launch_bounds__(512, 1) void k_scan(
    const float* __restrict__ D,        // layer-1 Ux' [T*B][1536]
    const uint4* __restrict__ W1zr, const uint4* __restrict__ W1hc,
    const uint4* __restrict__ W2zr, const uint4* __restrict__ W2hc,
    const uint4* __restrict__ I2zr, const uint4* __restrict__ I2hc,
    const float* __restrict__ bias1, const float* __restrict__ bias2,
    const float* __restrict__ h0,
    float* __restrict__ outbuf,         // out2 [T][64][512]
    float* __restrict__ hlast,          // [2][64][512]
    unsigned long long* __restrict__ h1S,   // [64][512]
    unsigned long long* __restrict__ wv1S,  // [64][512]
    unsigned long long* __restrict__ h2S,   // [64][512]
    unsigned long long* __restrict__ wv2S,  // [64][512]
    unsigned long long* __restrict__ n1S,   // [64][4][32]
    unsigned long long* __restrict__ n2S)   // [64][4][32]
{
  const int blk = blockIdx.x;
  const int b = blk & 63, w = blk >> 6;
  const int tid = threadIdx.x;
  const int lane = tid & 63, wave = tid >> 6;
  __shared__ __align__(16) __half hh1[H_], hh2[H_], wvh1[H_], wvh2[H_];
  __shared__ __align__(16) float hf1[H_], hf2[H_];
  __shared__ __align__(16) float ph1[512], ph2[512], phI1[512], phI2[512];
  __shared__ __align__(16) float red1[96], red2[96], redN[32];
  __shared__ __align__(16) float redW1[8], redW2[8];
  __shared__ __align__(16) float xr1[16], xr2[16], xrN[16];

  unsigned long long* h1Row  = h1S  + b*512;
  unsigned long long* wv1Row = wv1S + b*512;
  unsigned long long* h2Row  = h2S  + b*512;
  unsigned long long* wv2Row = wv2S + b*512;
  unsigned long long* n1Row  = n1S + b*128;
  unsigned long long* n2Row  = n2S + b*128;

  // ---- weight slices (streamed from L2 by compiler; off critical path)
  const int ks = tid >> 8;
  const int c2 = tid & 127, q = tid >> 7;
  const uint4* wA1b = W1zr + (size_t)w*32*512 + tid;
  const uint4* wB1b = W1hc + ((size_t)(w*4 + q)*16)*128 + c2;
  const uint4* wA2b = W2zr + (size_t)w*32*512 + tid;
  const uint4* wB2b = W2hc + ((size_t)(w*4 + q)*16)*128 + c2;
  const uint4* iAb  = I2zr + (size_t)w*32*512 + tid;
  const uint4* iBb  = I2hc + ((size_t)(w*4 + q)*16)*128 + c2;
  uint4 wA1[32], wA2[32], iA[32];
  #pragma unroll
  for (int i = 0; i < 32; i++){ wA1[i] = wA1b[i*512]; wA2[i] = wA2b[i*512]; iA[i] = iAb[i*512]; }
  uint4 wB1[16], wB2[16], iB[16];
  #pragma unroll
  for (int i = 0; i < 16; i++){ wB1[i] = wB1b[i*128]; wB2[i] = wB2b[i*128]; iB[i] = iBb[i*128]; }

  // initial h for both layers
  {
    const float a0 = h0[b*H_ + tid];
    hf1[tid] = a0; hh1[tid] = __float2half_rn(a0);
    const float a1 = h0[B_*H_ + b*H_ + tid];
    hf2[tid] = a1; hh2[tid] = __float2half_rn(a1);
  }
  const int jg = 128*w + (tid & 127);
  const bool isZ = (tid < 128);
  const bool isGate = (tid < 256);
  const float bval1 = isGate ? (isZ ? bias1[1024 + jg] : bias1[jg]) : 0.f;
  const float bcj1  = isZ ? bias1[512 + jg] : 0.f;
  const float bval2 = isGate ? (isZ ? bias2[1024 + jg] : bias2[jg]) : 0.f;
  const float bcj2  = isZ ? bias2[512 + jg] : 0.f;
  float B2own1, BC21, B2own2, BC22;
  {
    const float vz1 = bias1[1024+tid], vr1 = bias1[tid], vc1 = bias1[512+tid];
    const float vz2 = bias2[1024+tid], vr2 = bias2[tid], vc2 = bias2[512+tid];
    float vb[6] = { vz1*vz1, vr1*vr1, vc1*vc1, vz2*vz2, vr2*vr2, vc2*vc2 };
    wave_reduce_store<6>(vb, red1, tid);
    __syncthreads();
    const float B2z1 = sum8(red1),    B2r1 = sum8(red1+8);
    BC21 = sum8(red1+16);
    const float B2z2 = sum8(red1+24), B2r2 = sum8(red1+32);
    BC22 = sum8(red1+40);
    B2own1 = isZ ? B2z1 : B2r1;
    B2own2 = isZ ? B2z2 : B2r2;
    __syncthreads();
  }

  const uint4* hh1_4 = (const uint4*)hh1;
  const uint4* hh2_4 = (const uint4*)hh2;
  const uint4* wv1_4 = (const uint4*)wvh1;
  const uint4* wv2_4 = (const uint4*)wvh2;
  const float* Dbase = D + (size_t)b * G3_;

  float zreg1 = 0.f, zreg2 = 0.f;
  for (int t = 0; t <= T_; t++){
    const bool L1 = (t < T_);
    const bool L2 = (t >= 1);
    const unsigned tg1 = (unsigned)(t + 1);   // layer-1 rounds
    const unsigned tg2 = (unsigned)t;         // layer-2 rounds (step t-1)
    float yg1 = 0.f, yc1 = 0.f;
    if (L1){
      const float* U = Dbase + (size_t)t * (B_ * G3_);
      yg1 = isGate ? U[(isZ ? 1024 : 0) + jg] : 0.f;
      yc1 = isZ ? U[512 + jg] : 0.f;
    }

    // ---- gathers: h1_{t-1} (tag t), h2_{t-2} (tag t-1)
    if (t > 0){
      const float hv = pollf(h1Row + tid, (unsigned)t);
      hf1[tid] = hv; hh1[tid] = __float2half_rn(hv);
    }
    if (t >= 2){
      const float hv = pollf(h2Row + tid, (unsigned)(t-1));
      hf2[tid] = hv; hh2[tid] = __float2half_rn(hv);
    }
    __syncthreads();                                   // BAR A
    const float hv1 = hf1[tid];
    const float hv2 = hf2[tid];

    // ---- L2 ih dots (Wih2 x hh1): z/r half-k + c quarter-k
    if (L2){
      float p1 = 0.f;
      #pragma unroll
      for (int i = 0; i < 32; i++){
        const uint4 wr = iA[i]; const uint4 hp = hh1_4[ks*32 + i];
        p1 = fdot2_(wr.x, hp.x, p1); p1 = fdot2_(wr.y, hp.y, p1);
        p1 = fdot2_(wr.z, hp.z, p1); p1 = fdot2_(wr.w, hp.w, p1);
      }
      phI1[tid] = p1;
      float p2 = 0.f;
      #pragma unroll
      for (int i = 0; i < 16; i++){
        const uint4 wr = iB[i]; const uint4 hp = hh1_4[q*16 + i];
        p2 = fdot2_(wr.x, hp.x, p2); p2 = fdot2_(wr.y, hp.y, p2);
        p2 = fdot2_(wr.z, hp.z, p2); p2 = fdot2_(wr.w, hp.w, p2);
      }
      phI2[tid] = p2;
    }
    __syncthreads();                                   // BAR B
    // ---- ihN local reduce (3 col-split raw^2 sums + local |h2|^2)
    float rawzr = 0.f, rawc = 0.f;
    if (L2){
      if (isGate) rawzr = phI1[tid] + phI1[tid + 256];
      if (isZ)    rawc  = phI2[tid] + phI2[tid+128] + phI2[tid+256] + phI2[tid+384];
    }
    {
      float v[4] = { isZ ? rawzr*rawzr : 0.f,
                     (isGate && !isZ) ? rawzr*rawzr : 0.f,
                     isZ ? rawc*rawc : 0.f,
                     hv2*hv2 };
      wave_reduce_store<4>(v, redN, tid);
    }
    __syncthreads();                                   // BAR C
    if (L2 && wave == 1 && lane < 3){
      float s = 0.f; const float* r = redN + lane*8;
      #pragma unroll
      for (int i = 0; i < 8; i++) s += r[i];
      postf(n2Row + w*32 + lane, s, tg2);              // flight: ihN
    }
    // ---- L1 phase-A dots
    if (L1){
      float ap = 0.f;
      #pragma unroll
      for (int i = 0; i < 32; i++){
        const uint4 wr = wA1[i]; const uint4 hp = hh1_4[ks*32 + i];
        ap = fdot2_(wr.x, hp.x, ap); ap = fdot2_(wr.y, hp.y, ap);
        ap = fdot2_(wr.z, hp.z, ap); ap = fdot2_(wr.w, hp.w, ap);
      }
      ph1[tid] = ap;
    }
    __syncthreads();                                   // BAR D
    float a1 = 0.f;
    if (L1 && isGate) a1 = ph1[tid] + ph1[tid + 256];
    {
      float v[11];
      v[0] = hv1*hv1;
      #pragma unroll
      for (int s = 1; s < 11; s++) v[s] = 0.f;
      if (L1 && isGate){
        const int o = isZ ? 1 : 6;
        v[o] = a1*a1; v[o+1] = a1*yg1; v[o+2] = yg1*yg1; v[o+3] = a1*bval1; v[o+4] = yg1*bval1;
      }
      wave_reduce_store<11>(v, red1, tid);
    }
    __syncthreads();                                   // BAR E
    if (L1 && wave == 0 && lane < 10){
      float s = 0.f; const float* r = red1 + (1 + lane)*8;
      #pragma unroll
      for (int i = 0; i < 8; i++) s += r[i];
      postf(n1Row + w*32 + lane, s, tg1);              // flight: S1
    }
    // ---- L2 phase-A dots (Whh2 x hh2) hide the S1/ihN flights
    if (L2){
      float ap = 0.f;
      #pragma unroll
      for (int i = 0; i < 32; i++){
        const uint4 wr = wA2[i]; const uint4 hp = hh2_4[ks*32 + i];
        ap = fdot2_(wr.x, hp.x, ap); ap = fdot2_(wr.y, hp.y, ap);
        ap = fdot2_(wr.z, hp.z, ap); ap = fdot2_(wr.w, hp.w, ap);
      }
      ph2[tid] = ap;
    }
    if (L2 && wave == 1){
      const int wgi = lane >> 4, s = lane & 15;
      float v = (s < 3) ? pollf(n2Row + wgi*32 + s, tg2) : 0.f;
      v += __shfl_xor(v, 16); v += __shfl_xor(v, 32);
      if (lane < 16) xrN[lane] = v;
    }
    if (L1 && wave == 0){
      const int wgi = lane >> 4, s = lane & 15;
      float v = (s < 10) ? pollf(n1Row + wgi*32 + s, tg1) : 0.f;
      v += __shfl_xor(v, 16); v += __shfl_xor(v, 32);
      if (lane < 16) xr1[lane] = v;
    }
    __syncthreads();                                   // BAR F
    const float H2x  = sum8(red1);       // |h1_{t-1}|^2 (l1's H2, l2's x-norm^2)
    const float H2h2 = sum8(redN + 24);  // |h2_{t-2}|^2
    const float xn1 = fmaxf(sqrtf(H2x), EPSF);
    const float art1 = artanh_c(xn1);

    // ---- L1 gates + wv1 post
    if (L1 && isGate){
      const int o = isZ ? 0 : 5;
      const float g = gate_val(a1, yg1, bval1, xr1[o], xr1[o+1], xr1[o+2],
                               xr1[o+3], xr1[o+4], B2own1, xn1, art1);
      if (isZ) zreg1 = g;
      else postf(wv1Row + jg, g * hf1[jg], tg1);       // flight: wv1
    }
    // ---- L2 yg from ihN + a2 combine + S1' local reduce
    float yg2 = 0.f, yc2 = 0.f, a2 = 0.f;
    if (L2){
      if (isGate){
        const float S = isZ ? xrN[0] : xrN[1];
        const float rn = sqrtf(S);
        const float mn = fmaxf(rn, EPSF);
        const float sc = (rn <= EPSF) ? 0.f : (tanhf(mn/xn1*art1)/mn);
        yg2 = sc * rawzr;
      }
      if (isZ){
        const float rn = sqrtf(xrN[2]);
        const float mn = fmaxf(rn, EPSF);
        const float sc = (rn <= EPSF) ? 0.f : (tanhf(mn/xn1*art1)/mn);
        yc2 = sc * rawc;
      }
      if (isGate) a2 = ph2[tid] + ph2[tid + 256];
    }
    {
      float v[10];
      #pragma unroll
      for (int s = 0; s < 10; s++) v[s] = 0.f;
      if (L2 && isGate){
        const int o = isZ ? 0 : 5;
        v[o] = a2*a2; v[o+1] = a2*yg2; v[o+2] = yg2*yg2; v[o+3] = a2*bval2; v[o+4] = yg2*bval2;
      }
      wave_reduce_store<10>(v, red2, tid);
    }
    __syncthreads();                                   // BAR G
    if (L2 && wave == 1 && lane < 10){
      float s = 0.f; const float* r = red2 + lane*8;
      #pragma unroll
      for (int i = 0; i < 8; i++) s += r[i];
      postf(n2Row + w*32 + 3 + lane, s, tg2);          // flight: S1'
    }
    // ---- wv1 gather (all) ; wave1 then polls S1'
    float wvv1 = 0.f;
    if (L1) wvv1 = pollf(wv1Row + tid, tg1);
    wvh1[tid] = __float2half_rn(wvv1);
    if (L2 && wave == 1){
      const int wgi = lane >> 4, s = lane & 15;
      float v = (s < 10) ? pollf(n2Row + wgi*32 + 3 + s, tg2) : 0.f;
      v += __shfl_xor(v, 16); v += __shfl_xor(v, 32);
      if (lane < 16) xr2[lane] = v;
    }
    {
      float v1[1] = { wvv1*wvv1 };
      wave_reduce_store<1>(v1, redW1, tid);
    }
    __syncthreads();                                   // BAR H
    const float W2_1 = sum8(redW1);
    const float wraw1 = sqrtf(W2_1);
    const float wn1 = fmaxf(wraw1, EPSF);
    const float mu1 = (wraw1 <= EPSF) ? 0.f : (tanhf(wn1/xn1*art1)/wn1);
    const float rhn1 = fmaxf(mu1*wraw1, EPSF);
    const float xn2 = fmaxf(sqrtf(H2h2), EPSF);
    const float art2 = artanh_c(xn2);

    // ---- L2 gates + wv2 post ; L1 phase-B dots
    if (L2 && isGate){
      const int o = isZ ? 0 : 5;
      const float g = gate_val(a2, yg2, bval2, xr2[o], xr2[o+1], xr2[o+2],
                               xr2[o+3], xr2[o+4], B2own2, xn2, art2);
      if (isZ) zreg2 = g;
      else postf(wv2Row + jg, g * hf2[jg], tg2);       // flight: wv2
    }
    if (L1){
      float cp = 0.f;
      #pragma unroll
      for (int i = 0; i < 16; i++){
        const uint4 wr = wB1[i]; const uint4 rp = wv1_4[q*16 + i];
        cp = fdot2_(wr.x, rp.x, cp); cp = fdot2_(wr.y, rp.y, cp);
        cp = fdot2_(wr.z, rp.z, cp); cp = fdot2_(wr.w, rp.w, cp);
      }
      ph1[tid] = cp;
    }
    __syncthreads();                                   // BAR I
    // ---- L1 cel + S3 local ; wv2 gather (all)
    float cel1 = 0.f, hj1 = 0.f;
    if (L1 && isZ){
      cel1 = mu1 * (ph1[tid] + ph1[tid+128] + ph1[tid+256] + ph1[tid+384]);
      hj1  = hf1[jg];
    }
    float wvv2 = 0.f;
    if (L2) wvv2 = pollf(wv2Row + tid, tg2);
    wvh2[tid] = __float2half_rn(wvv2);
    {
      float v[8] = { cel1*cel1, cel1*yc1, yc1*yc1, cel1*bcj1, yc1*bcj1,
                     hj1*cel1, hj1*yc1, hj1*bcj1 };
      wave_reduce_store<8>(v, red1, tid);
    }
    {
      float v1[1] = { wvv2*wvv2 };
      wave_reduce_store<1>(v1, redW2, tid);
    }
    __syncthreads();                                   // BAR J
    if (L1 && wave == 0 && lane < 8){
      float s = 0.f; const float* r = red1 + lane*8;
      #pragma unroll
      for (int i = 0; i < 8; i++) s += r[i];
      postf(n1Row + w*32 + 10 + lane, s, tg1);         // flight: S3
    }
    // ---- L2 phase-B dots hide S3 flight
    if (L2){
      float cp = 0.f;
      #pragma unroll
      for (int i = 0; i < 16; i++){
        const uint4 wr = wB2[i]; const uint4 rp = wv2_4[q*16 + i];
        cp = fdot2_(wr.x, rp.x, cp); cp = fdot2_(wr.y, rp.y, cp);
        cp = fdot2_(wr.z, rp.z, cp); cp = fdot2_(wr.w, rp.w, cp);
      }
      ph2[tid] = cp;
    }
    if (L1 && wave == 0){
      const int wgi = lane >> 4, s = lane & 15;
      float v = (s < 8) ? pollf(n1Row + wgi*32 + 10 + s, tg1) : 0.f;
      v += __shfl_xor(v, 16); v += __shfl_xor(v, 32);
      if (lane < 16) xr1[lane] = v;
    }
    __syncthreads();                                   // BAR K
    const float W2_2 = sum8(redW2);
    const float wraw2 = sqrtf(W2_2);
    const float wn2 = fmaxf(wraw2, EPSF);
    const float mu2 = (wraw2 <= EPSF) ? 0.f : (tanhf(wn2/xn2*art2)/wn2);
    const float rhn2 = fmaxf(mu2*wraw2, EPSF);

    // ---- L1 candidate tail -> del1 ; L2 cel2 + S3' local
    float del1 = 0.f, w2el1 = 0.f;
    float cAf1 = 0.f, cBf1 = 0.f, idf1 = 0.f, nu1 = 0.f;
    if (L1){
      const float C2 = xr1[0], CY = xr1[1], Y2c = xr1[2], CB = xr1[3],
                  YBc = xr1[4], HC = xr1[5], HYd = xr1[6], HBd = xr1[7];
      const float craw = sqrtf(C2);
      const float cmn2 = fmaxf(craw, EPSF);
      const float alc = (craw <= EPSF) ? 0.f : (tanhf(cmn2/rhn1*artanh_c(rhn1))/cmn2);
      const float X2c = alc*alc*C2, XYc = alc*CY, XBc = alc*CB, HXc = alc*HC;
      const float cA1c = 1.f + 2.f*XYc + Y2c, cB1c = 1.f - X2c;
      const float den1c = fmaxf(1.f + 2.f*XYc + X2c*Y2c, EPSF), id1c = 1.f/den1c;
      const float T2c = fmaxf((cA1c*cA1c*X2c + 2.f*cA1c*cB1c*XYc + cB1c*cB1c*Y2c)*id1c*id1c, 0.f);
      const float TBc = (cA1c*XBc + cB1c*YBc)*id1c;
      const float HT1 = (cA1c*HXc + cB1c*HYd)*id1c;
      const float cA2c = 1.f + 2.f*TBc + BC21, cB2c = 1.f - T2c;
      const float den2c = fmaxf(1.f + 2.f*TBc + T2c*BC21, EPSF), id2c = 1.f/den2c;
      const float HTL2 = fmaxf((cA2c*cA2c*T2c + 2.f*cA2c*cB2c*TBc + cB2c*cB2c*BC21)*id2c*id2c, 0.f);
      const float HHTL = (cA2c*HT1 + cB2c*HBd)*id2c;
      const float cAd = 1.f - 2.f*HHTL + HTL2, cBd = 1.f - H2x;
      const float dend = fmaxf(1.f - 2.f*HHTL + H2x*HTL2, EPSF), idd = 1.f/dend;
      if (isZ){
        const float t1cel = (cA1c*(alc*cel1) + cB1c*yc1)*id1c;
        const float htlel = (cA2c*t1cel + cB2c*bcj1)*id2c;
        del1 = (cAd*(-hj1) + cBd*htlel)*idd;
        w2el1 = zreg1*del1;
      }
    }
    {
      float v[3] = { del1*del1, w2el1*w2el1, hj1*w2el1 };
      wave_reduce_store<3>(v, red1, tid);
    }
    float cel2 = 0.f, hj2 = 0.f;
    if (L2 && isZ){
      cel2 = mu2 * (ph2[tid] + ph2[tid+128] + ph2[tid+256] + ph2[tid+384]);
      hj2  = hf2[jg];
    }
    {
      float v[8] = { cel2*cel2, cel2*yc2, yc2*yc2, cel2*bcj2, yc2*bcj2,
                     hj2*cel2, hj2*yc2, hj2*bcj2 };
      wave_reduce_store<8>(v, red2, tid);
    }
    __syncthreads();                                   // BAR L
    if (L1 && wave == 0 && lane < 3){
      float s = 0.f; const float* r = red1 + lane*8;
      #pragma unroll
      for (int i = 0; i < 8; i++) s += r[i];
      postf(n1Row + w*32 + 18 + lane, s, tg1);         // flight: S4
    }
    if (L2 && wave == 1 && lane < 8){
      float s = 0.f; const float* r = red2 + lane*8;
      #pragma unroll
      for (int i = 0; i < 8; i++) s += r[i];
      postf(n2Row + w*32 + 13 + lane, s, tg2);         // flight: S3'
    }
    if (L1 && wave == 0){
      const int wgi = lane >> 4, s = lane & 15;
      float v = (s < 3) ? pollf(n1Row + wgi*32 + 18 + s, tg1) : 0.f;
      v += __shfl_xor(v, 16); v += __shfl_xor(v, 32);
      if (lane < 16) xr1[lane] = v;
    }
    if (L2 && wave == 1){
      const int wgi = lane >> 4, s = lane & 15;
      float v = (s < 8) ? pollf(n2Row + wgi*32 + 13 + s, tg2) : 0.f;
      v += __shfl_xor(v, 16); v += __shfl_xor(v, 32);
      if (lane < 16) xr2[lane] = v;
    }
    __syncthreads();                                   // BAR M
    // ---- L1 final -> post h1 ; L2 tail -> del2 + S4' local
    if (L1){
      const float D2v = xr1[0], W22 = xr1[1], HW = xr1[2];
      const float dnv = fmaxf(sqrtf(D2v), EPSF);
      const float w2raw = sqrtf(W22);
      const float w2n = fmaxf(w2raw, EPSF);
      nu1 = (w2raw <= EPSF) ? 0.f : (tanhf(w2n/dnv*artanh_c(dnv))/w2n);
      const float Y2f = nu1*nu1*W22, XYf = nu1*HW;
      cAf1 = 1.f + 2.f*XYf + Y2f; cBf1 = 1.f - H2x;
      const float denf = fmaxf(1.f + 2.f*XYf + H2x*Y2f, EPSF); idf1 = 1.f/denf;
      if (isZ){
        const float hnew = (cAf1*hj1 + cBf1*(nu1*w2el1))*idf1;
        postf(h1Row + jg, hnew, tg1);
        if (t == T_-1) hlast[b*H_ + jg] = hnew;
      }
    }
    float del2 = 0.f, w2el2 = 0.f;
    float cA1c2=0.f,cB1c2=0.f,id1c2=0.f,cA2c2=0.f,cB2c2=0.f,id2c2=0.f,
          cAd2=0.f,cBd2=0.f,idd2=0.f,alc2=0.f;
    if (L2){
      const float C2 = xr2[0], CY = xr2[1], Y2c = xr2[2], CB = xr2[3],
                  YBc = xr2[4], HC = xr2[5], HYd = xr2[6], HBd = xr2[7];
      const float craw = sqrtf(C2);
      const float cmn2 = fmaxf(craw, EPSF);
      alc2 = (craw <= EPSF) ? 0.f : (tanhf(cmn2/rhn2*artanh_c(rhn2))/cmn2);
      const float X2c = alc2*alc2*C2, XYc = alc2*CY, XBc = alc2*CB, HXc = alc2*HC;
      cA1c2 = 1.f + 2.f*XYc + Y2c; cB1c2 = 1.f - X2c;
      const float den1c = fmaxf(1.f + 2.f*XYc + X2c*Y2c, EPSF); id1c2 = 1.f/den1c;
      const float T2c = fmaxf((cA1c2*cA1c2*X2c + 2.f*cA1c2*cB1c2*XYc + cB1c2*cB1c2*Y2c)*id1c2*id1c2, 0.f);
      const float TBc = (cA1c2*XBc + cB1c2*YBc)*id1c2;
      const float HT1 = (cA1c2*HXc + cB1c2*HYd)*id1c2;
      cA2c2 = 1.f + 2.f*TBc + BC22; cB2c2 = 1.f - T2c;
      const float den2c = fmaxf(1.f + 2.f*TBc + T2c*BC22, EPSF); id2c2 = 1.f/den2c;
      const float HTL2 = fmaxf((cA2c2*cA2c2*T2c + 2.f*cA2c2*cB2c2*TBc + cB2c2*cB2c2*BC22)*id2c2*id2c2, 0.f);
      const float HHTL = (cA2c2*HT1 + cB2c2*HBd)*id2c2;
      cAd2 = 1.f - 2.f*HHTL + HTL2; cBd2 = 1.f - H2h2;
      const float dend = fmaxf(1.f - 2.f*HHTL + H2h2*HTL2, EPSF); idd2 = 1.f/dend;
      if (isZ){
        const float t1cel = (cA1c2*(alc2*cel2) + cB1c2*yc2)*id1c2;
        const float htlel = (cA2c2*t1cel + cB2c2*bcj2)*id2c2;
        del2 = (cAd2*(-hj2) + cBd2*htlel)*idd2;
        w2el2 = zreg2*del2;
      }
    }
    {
      float v[3] = { del2*del2, w2el2*w2el2, hj2*w2el2 };
      wave_reduce_store<3>(v, red2, tid);
    }
    __syncthreads();                                   // BAR N
    if (L2 && wave == 1 && lane < 3){
      float s = 0.f; const float* r = red2 + lane*8;
      #pragma unroll
      for (int i = 0; i < 8; i++) s += r[i];
      postf(n2Row + w*32 + 21 + lane, s, tg2);
    }
    if (L2 && wave == 1){
      const int wgi = lane >> 4, s = lane & 15;
      float v = (s < 3) ? pollf(n2Row + wgi*32 + 21 + s, tg2) : 0.f;
      v += __shfl_xor(v, 16); v += __shfl_xor(v, 32);
      if (lane < 16) xr2[lane] = v;
    }
    __syncthreads();                                   // BAR O
    if (L2){
      const float D2v = xr2[0], W22 = xr2[1], HW = xr2[2];
      const float dnv = fmaxf(sqrtf(D2v), EPSF);
      const float w2raw = sqrtf(W22);
      const float w2n = fmaxf(w2raw, EPSF);
      const float nu = (w2raw <= EPSF) ? 0.f : (tanhf(w2n/dnv*artanh_c(dnv))/w2n);
      const float Y2f = nu*nu*W22, XYf = nu*HW;
      const float cAf = 1.f + 2.f*XYf + Y2f, cBf = 1.f - H2h2;
      const float denf = fmaxf(1.f + 2.f*XYf + H2h2*Y2f, EPSF), idf = 1.f/denf;
      if (isZ){
        const float hnew = (cAf*hj2 + cBf*(nu*w2el2))*idf;
        outbuf[(size_t)((t-1)*B_ + b)*H_ + jg] = hnew;
        postf(h2Row + jg, hnew, tg2);
        if (t == T_) hlast[B_*H_ + b*H_ + jg] = hnew;
      }
    }
  }
}

extern "C" void kernel_launch(void* const* d_in, const int* in_sizes, int n_in,
                              void* d_out, int out_size, void* d_ws, size_t ws_size,
                              hipStream_t stream){
  (void)in_sizes; (void)n_in; (void)out_size; (void)ws_size;
  const float* input = (const float*)d_in[0];
  const float* h0    = (const float*)d_in[1];
  const float* wih1  = (const float*)d_in[2];
  const float* wih2  = (const float*)d_in[3];
  const float* whh1  = (const float*)d_in[4];
  const float* whh2  = (const float*)d_in[5];
  const float* bias1 = (const float*)d_in[6];
  const float* bias2 = (const float*)d_in[7];
  float* out = (float*)d_out;

  // ws layout (floats): A_ 786432 (WihT, later reused for W2+I2 packs) |
  // Dbuf 25165824 | W1zr 262144 | W1hc 131072 | comm 294912 (147456 u64)
  float* A_    = (float*)d_ws;
  float* Dbuf  = A_ + 786432;
  uint4* W1zr  = (uint4*)(Dbuf + 25165824);
  uint4* W1hc  = W1zr + 65536;
  unsigned long long* comm = (unsigned long long*)(W1hc + 32768);
  unsigned long long* h1S  = comm;            // 32768
  unsigned long long* wv1S = h1S  + 32768;    // 32768
  unsigned long long* h2S  = wv1S + 32768;    // 32768
  unsigned long long* wv2S = h2S  + 32768;    // 32768
  unsigned long long* n1S  = wv2S + 32768;    // 8192
  unsigned long long* n2S  = n1S  + 8192;     // 8192
  // A_ reused after k_gemm: W2zr 65536 u4 | W2hc 32768 | I2zr 65536 | I2hc 32768
  uint4* W2zr = (uint4*)A_;
  uint4* W2hc = W2zr + 65536;
  uint4* I2zr = W2hc + 32768;
  uint4* I2hc = I2zr + 65536;

  float* ht = out + (size_t)T_ * B_ * H_;

  // layer-1 prep (WihT lives in A_ until k_gemm consumes it)
  k_prep_ih<<<3072, 256, 0, stream>>>(wih1, A_);
  k_gemm<<<dim3(256, 24), 256, 0, stream>>>(input, A_, Dbuf);
  k_nonlin<<<T_*B_, 64, 0, stream>>>(input, Dbuf);
  // weight packs (W2/I2 overwrite A_ AFTER gemm -- stream-ordered)
  k_prep_hhR<<<384, 256, 0, stream>>>(whh1, W1zr, W1hc);
  k_prep_hhR<<<384, 256, 0, stream>>>(whh2, W2zr, W2hc);
  k_prep_hhR<<<384, 256, 0, stream>>>(wih2, I2zr, I2hc);

  // fused two-layer scan (257 iterations; layer-2 trails by one step)
  k_scan<<<256, 512, 0, stream>>>(Dbuf, W1zr, W1hc, W2zr, W2hc, I2zr, I2hc,
                                  bias1, bias2, h0, out, ht,
                                  h1S, wv1S, h2S, wv2S, n1S, n2S);
}

// Round 8
// 7784.920 us; speedup vs baseline: 2.1583x; 2.1583x over previous
//
#include <hip/hip_runtime.h>
#include <hip/hip_fp16.h>
#include <math.h>
#include <stdint.h>

// MobiusGRU T=256 B=64 D=H=512, 2 layers.
// R15 = R7 (verified best, 3340us/scan) with ONE change: k_scan is compiled
// with amdgpu_waves_per_eu(2,2) instead of __launch_bounds__(512,1).
// Rationale: grid = 256 WGs on 256 CUs -> exactly 8 waves/CU (2/SIMD) no
// matter what, which supports 256 VGPRs/lane. The compiler's occupancy
// heuristic nevertheless allocated only 128 VGPRs (measured), below the 192
// VGPRs of declared per-thread weight slices (48 x uint4), forcing a 384KB/WG
// L2 re-stream of weights EVERY t-step (~25GB/scan) with dependent-load
// latency inside every dot phase. waves_per_eu(2,2) pins the budget at 256
// so the weight slices become truly register-resident at zero occupancy cost.
// Everything else (comm fabric, 5 tagged exchange rounds/step, col-split
// dots) is byte-identical to R7.

#define T_  256
#define B_  64
#define H_  512
#define G3_ 1536
#define EPSF 1e-15f
#define CLIPF (1.0f - 1e-5f)
#define SCOPE_AGENT __HIP_MEMORY_SCOPE_AGENT

typedef _Float16 v2h __attribute__((ext_vector_type(2)));

__device__ __forceinline__ float fdot2_(unsigned int w, unsigned int h, float c){
#if __has_builtin(__builtin_amdgcn_fdot2)
  return __builtin_amdgcn_fdot2(__builtin_bit_cast(v2h, w), __builtin_bit_cast(v2h, h), c, false);
#else
  const __half2 wh = __builtin_bit_cast(__half2, w);
  const __half2 hh = __builtin_bit_cast(__half2, h);
  return c + __low2float(wh)*__low2float(hh) + __high2float(wh)*__high2float(hh);
#endif
}

__device__ __forceinline__ float artanh_c(float x){
  x = fminf(fmaxf(x, -CLIPF), CLIPF);
  return 0.5f * logf((1.0f + x) / (1.0f - x));
}
__device__ __forceinline__ float sigmoidf_(float x){ return 1.0f/(1.0f+expf(-x)); }
__device__ __forceinline__ float hsum4(float4 v){ return (v.x+v.y)+(v.z+v.w); }

// fence-free tagged exchange (relaxed agent atomics)
__device__ __forceinline__ void postf(unsigned long long* p, float x, unsigned tag){
  unsigned long long v = ((unsigned long long)tag << 32) |
                         (unsigned long long)__float_as_uint(x);
  __hip_atomic_store(p, v, __ATOMIC_RELAXED, SCOPE_AGENT);
}
__device__ __forceinline__ float pollf(const unsigned long long* p, unsigned tag){
  unsigned long long v = __hip_atomic_load(p, __ATOMIC_RELAXED, SCOPE_AGENT);
  while ((unsigned)(v >> 32) != tag)
    v = __hip_atomic_load(p, __ATOMIC_RELAXED, SCOPE_AGENT);
  return __uint_as_float((unsigned)v);
}

// reduce NS values across the wave; lane0 stores red[s*8 + wave] (8 waves)
template<int NS>
__device__ __forceinline__ void wave_reduce_store(float (&v)[NS], float* red, int tid){
  #pragma unroll
  for (int off = 32; off > 0; off >>= 1)
    #pragma unroll
    for (int s = 0; s < NS; s++) v[s] += __shfl_xor(v[s], off);
  if ((tid & 63) == 0)
    #pragma unroll
    for (int s = 0; s < NS; s++) red[s*8 + (tid >> 6)] = v[s];
}

// ---- transpose weight_ih [1536][512] -> WihT [512][1536]
__global__ void k_prep_ih(const float* __restrict__ Wih, float* __restrict__ WihT){
  int i = blockIdx.x * blockDim.x + threadIdx.x;
  if (i >= H_ * G3_) return;
  int k = i / G3_, n = i % G3_;
  WihT[i] = Wih[n * H_ + k];
}

__device__ __forceinline__ uint4 pack8h(const float* s){
  __half2 p0 = __halves2half2(__float2half_rn(s[0]), __float2half_rn(s[1]));
  __half2 p1 = __halves2half2(__float2half_rn(s[2]), __float2half_rn(s[3]));
  __half2 p2 = __halves2half2(__float2half_rn(s[4]), __float2half_rn(s[5]));
  __half2 p3 = __halves2half2(__float2half_rn(s[6]), __float2half_rn(s[7]));
  uint4 r;
  r.x = __builtin_bit_cast(unsigned int, p0);
  r.y = __builtin_bit_cast(unsigned int, p1);
  r.z = __builtin_bit_cast(unsigned int, p2);
  r.w = __builtin_bit_cast(unsigned int, p3);
  return r;
}

// ---- weight_hh -> register-resident layouts (f16, 8-k-wide uint4)
__global__ void k_prep_hhR(const float* __restrict__ Whh, uint4* __restrict__ WzrR,
                           uint4* __restrict__ WhcR){
  int i = blockIdx.x * blockDim.x + threadIdx.x;   // 98304 total
  if (i < 65536){
    int w = i >> 14, rem = i & 16383;
    int ii = rem >> 9, tid = rem & 511;
    int c = tid & 255, ks = tid >> 8;
    int j = 128*w + (c & 127);
    int row = (c < 128) ? (1024 + j) : j;
    int k0 = ks*256 + ii*8;
    WzrR[i] = pack8h(Whh + row*H_ + k0);
  } else {
    int e = i - 65536;                              // 32768
    int w = e >> 13, rem = e & 8191;
    int q = rem >> 11, rem2 = rem & 2047;
    int ii = rem2 >> 7, c = rem2 & 127;
    int row = 512 + 128*w + c;
    int k0 = q*128 + ii*8;
    WhcR[e] = pack8h(Whh + row*H_ + k0);
  }
}

// ---- tiled f32 GEMM: C[16384][1536] = A[16384][512] * Bt[512][1536]
__global__ __launch_bounds__(256) void k_gemm(const float* __restrict__ A,
                                              const float* __restrict__ Bt,
                                              float* __restrict__ C){
  const int N = G3_, K = H_;
  const int mbase = blockIdx.x * 64, nbase = blockIdx.y * 64;
  __shared__ float As[32][65];
  __shared__ float Bs[32][65];
  const int tid = threadIdx.x;
  const int tm = tid >> 4, tn = tid & 15;
  float acc[4][4] = {};
  for (int k0 = 0; k0 < K; k0 += 32){
    #pragma unroll
    for (int i = 0; i < 8; i++){
      int e = tid + 256*i;
      int m = e >> 5, k = e & 31;
      As[k][m] = A[(size_t)(mbase + m) * K + k0 + k];
      int kk = e >> 6, n = e & 63;
      Bs[kk][n] = Bt[(size_t)(k0 + kk) * N + nbase + n];
    }
    __syncthreads();
    #pragma unroll
    for (int kk = 0; kk < 32; kk++){
      float av[4], bv[4];
      #pragma unroll
      for (int i = 0; i < 4; i++) av[i] = As[kk][tm*4+i];
      #pragma unroll
      for (int j = 0; j < 4; j++) bv[j] = Bs[kk][tn*4+j];
      #pragma unroll
      for (int i = 0; i < 4; i++)
        #pragma unroll
        for (int j = 0; j < 4; j++)
          acc[i][j] = fmaf(av[i], bv[j], acc[i][j]);
    }
    __syncthreads();
  }
  #pragma unroll
  for (int i = 0; i < 4; i++)
    #pragma unroll
    for (int j = 0; j < 4; j++)
      C[(size_t)(mbase + tm*4 + i) * N + nbase + tn*4 + j] = acc[i][j];
}

// ---- mobius_matvec tail on Ux rows
__global__ void k_nonlin(const float* __restrict__ X, float* __restrict__ D){
  const int row = blockIdx.x;
  const int lane = threadIdx.x;
  const float* x = X + (size_t)row * H_;
  float s = 0.0f;
  for (int k = lane; k < H_; k += 64){ float v = x[k]; s = fmaf(v, v, s); }
  #pragma unroll
  for (int off = 32; off > 0; off >>= 1) s += __shfl_xor(s, off);
  const float xn = fmaxf(sqrtf(s), EPSF);
  const float art = artanh_c(xn);
  float* drow = D + (size_t)row * G3_;
  for (int g = 0; g < 3; g++){
    float* mx = drow + g * H_;
    float s2 = 0.0f;
    for (int k = lane; k < H_; k += 64){ float v = mx[k]; s2 = fmaf(v, v, s2); }
    #pragma unroll
    for (int off = 32; off > 0; off >>= 1) s2 += __shfl_xor(s2, off);
    const float raw = sqrtf(s2);
    const float mn = fmaxf(raw, EPSF);
    const float scale = (raw <= EPSF) ? 0.0f : (tanhf(mn / xn * art) / mn);
    for (int k = lane; k < H_; k += 64) mx[k] *= scale;
  }
}

// ---- scan: 4 WGs/row (256 WGs x 512 thr), weights pinned in VGPRs
__global__ __attribute__((amdgpu_flat_work_group_size(512, 512),
                          amdgpu_waves_per_eu(2, 2)))
void k_scan(
    const float* __restrict__ D,        // Ux' [T*B][1536]: r|c|z col blocks
    const uint4* __restrict__ WzrR,     // [4][32][512]
    const uint4* __restrict__ WhcR,     // [4][4][16][128]
    const float* __restrict__ bias,     // [3][512] = b_r, b_c, b_z
    const float* __restrict__ h0,
    float* __restrict__ outbuf,         // [T][64][512]
    float* __restrict__ hlast,
    unsigned long long* __restrict__ hS,    // [64][512]
    unsigned long long* __restrict__ wvS,   // [64][512]
    unsigned long long* __restrict__ S1s,   // [64][4][16]
    unsigned long long* __restrict__ S3s,   // [64][4][16]
    unsigned long long* __restrict__ S4s)   // [64][4][16]
{
  const int blk = blockIdx.x;
  const int b = blk & 63, w = blk >> 6;
  const int tid = threadIdx.x;
  const int lane = tid & 63, wave = tid >> 6;
  __shared__ __align__(16) __half hh[H_];
  __shared__ __align__(16) float hf[H_];
  __shared__ __align__(16) __half wvh[H_];
  __shared__ __align__(16) float ph[512];
  __shared__ __align__(16) float red[96];
  __shared__ __align__(16) float redW[8];
  __shared__ __align__(16) float xr[16];

  unsigned long long* hRow  = hS  + b*512;
  unsigned long long* wvRow = wvS + b*512;
  unsigned long long* s1Row = S1s + b*64;
  unsigned long long* s3Row = S3s + b*64;
  unsigned long long* s4Row = S4s + b*64;

  // ---- preload weight slices into registers (256-VGPR budget: resident)
  const int ks = tid >> 8;                      // phase A k-half
  const int c2 = tid & 127, q = tid >> 7;       // phase B: col + k-quarter
  const uint4* wAb = WzrR + (size_t)w*32*512 + tid;
  const uint4* wBb = WhcR + ((size_t)(w*4 + q)*16)*128 + c2;
  uint4 wA[32];
  #pragma unroll
  for (int i = 0; i < 32; i++) wA[i] = wAb[i*512];
  uint4 wB[16];
  #pragma unroll
  for (int i = 0; i < 16; i++) wB[i] = wBb[i*128];

  // initial h
  {
    const float hv0 = h0[b*H_ + tid];
    hf[tid] = hv0;
    hh[tid] = __float2half_rn(hv0);
  }
  // bias values + (local) bias norms
  const int jg = 128*w + (tid & 127);           // gate/cand col for tid<256 / tid<128
  const bool isZ = (tid < 128);
  const bool isGate = (tid < 256);
  const float bval = isGate ? (isZ ? bias[1024 + jg] : bias[jg]) : 0.f;
  const float bcj  = isZ ? bias[512 + jg] : 0.f;
  float B2own, BC2;
  {
    const float vz = bias[1024 + tid], vr = bias[tid], vc = bias[512 + tid];
    float vb[3] = { vz*vz, vr*vr, vc*vc };
    wave_reduce_store<3>(vb, red, tid);
    __syncthreads();
    const float4* p = (const float4*)red;
    const float B2z = hsum4(p[0]) + hsum4(p[1]);
    const float B2r = hsum4(p[2]) + hsum4(p[3]);
    BC2 = hsum4(p[4]) + hsum4(p[5]);
    B2own = isZ ? B2z : B2r;
    __syncthreads();
  }

  const uint4* hh4 = (const uint4*)hh;
  const uint4* wv4 = (const uint4*)wvh;
  const float* Dbase = D + (size_t)b * G3_;

  float zreg = 0.f;
  for (int t = 0; t < T_; t++){
    const unsigned tag = (unsigned)(t + 1);
    const float* U = Dbase + (size_t)t * (B_ * G3_);
    // Ux loads issue early
    const float yg = isGate ? U[(isZ ? 1024 : 0) + jg] : 0.f;
    const float yc = isZ ? U[512 + jg] : 0.f;

    // ---- h gather (posted with tag t by step t-1)
    if (t > 0){
      const float hv = pollf(hRow + tid, (unsigned)t);
      hf[tid] = hv;
      hh[tid] = __float2half_rn(hv);
    }
    __syncthreads();                                   // bar1
    const float hv = hf[tid];

    // ---- phase A: register x LDS-broadcast dot (col tid&255, k-half ks)
    float ap = 0.f;
    #pragma unroll
    for (int i = 0; i < 32; i++){
      const uint4 wr = wA[i];
      const uint4 hp = hh4[ks*32 + i];
      ap = fdot2_(wr.x, hp.x, ap);
      ap = fdot2_(wr.y, hp.y, ap);
      ap = fdot2_(wr.z, hp.z, ap);
      ap = fdot2_(wr.w, hp.w, ap);
    }
    ph[tid] = ap;
    __syncthreads();                                   // bar2
    const float a = isGate ? (ph[tid] + ph[tid + 256]) : 0.f;

    // ---- S1: local 11-slot reduce (slot0=h2 local-only; 10 gate dots exchanged)
    {
      float v[11];
      v[0] = hv*hv;
      #pragma unroll
      for (int s = 1; s < 11; s++) v[s] = 0.f;
      if (isGate){
        const int o = isZ ? 1 : 6;
        v[o] = a*a; v[o+1] = a*yg; v[o+2] = yg*yg; v[o+3] = a*bval; v[o+4] = yg*bval;
      }
      wave_reduce_store<11>(v, red, tid);
    }
    __syncthreads();                                   // bar3
    float H2;
    { const float4* p = (const float4*)red; H2 = hsum4(p[0]) + hsum4(p[1]); }
    if (wave == 0 && lane < 10){
      float s = 0.f;
      const float* r = red + (1 + lane)*8;
      #pragma unroll
      for (int i = 0; i < 8; i++) s += r[i];
      postf(s1Row + w*16 + lane, s, tag);
    }
    if (wave == 0){
      const int wgi = lane >> 4, s = lane & 15;
      float v = (s < 10) ? pollf(s1Row + wgi*16 + s, tag) : 0.f;
      v += __shfl_xor(v, 16);
      v += __shfl_xor(v, 32);
      if (lane < 16) xr[lane] = v;
    }
    __syncthreads();                                   // bar4

    // ---- gate math (threads 0..255)
    const float xn = fmaxf(sqrtf(H2), EPSF);
    const float art_h = artanh_c(xn);
    if (isGate){
      const int o = isZ ? 0 : 5;
      const float A2 = xr[o], AY = xr[o+1], Yy2 = xr[o+2], AB = xr[o+3], YB = xr[o+4];
      const float mraw = sqrtf(A2);
      const float mnc = fmaxf(mraw, EPSF);
      const float alpha = (mraw <= EPSF) ? 0.f : (tanhf(mnc/xn*art_h)/mnc);
      const float X2 = alpha*alpha*A2, XY = alpha*AY, XB = alpha*AB;
      const float cA1 = 1.f + 2.f*XY + Yy2, cB1 = 1.f - X2;
      const float den1 = fmaxf(1.f + 2.f*XY + X2*Yy2, EPSF), id1 = 1.f/den1;
      const float T2 = fmaxf((cA1*cA1*X2 + 2.f*cA1*cB1*XY + cB1*cB1*Yy2)*id1*id1, 0.f);
      const float TB = (cA1*XB + cB1*YB)*id1;
      const float cA2 = 1.f + 2.f*TB + B2own, cB2 = 1.f - T2;
      const float den2 = fmaxf(1.f + 2.f*TB + T2*B2own, EPSF), id2 = 1.f/den2;
      const float U2 = fmaxf((cA2*cA2*T2 + 2.f*cA2*cB2*TB + cB2*cB2*B2own)*id2*id2, 0.f);
      const float un = fmaxf(sqrtf(U2), EPSF);
      const float lsc = artanh_c(un)/un;
      const float t1el = (cA1*(alpha*a) + cB1*yg)*id1;
      const float uel  = (cA2*t1el + cB2*bval)*id2;
      const float g = sigmoidf_(lsc*uel);
      if (isZ) zreg = g;
      else postf(wvRow + jg, g * hf[jg], tag);
    }
    // ---- wv gather + local W2 reduce
    const float wvv = pollf(wvRow + tid, tag);
    wvh[tid] = __float2half_rn(wvv);
    {
      float v1[1] = { wvv*wvv };
      wave_reduce_store<1>(v1, redW, tid);
    }
    __syncthreads();                                   // bar5
    float W2;
    { const float4* p = (const float4*)redW; W2 = hsum4(p[0]) + hsum4(p[1]); }
    const float wraw = sqrtf(W2);
    const float wn = fmaxf(wraw, EPSF);
    const float mu = (wraw <= EPSF) ? 0.f : (tanhf(wn/xn*art_h)/wn);
    const float rhn = fmaxf(mu*wraw, EPSF);

    // ---- phase B: register x LDS-broadcast dot (col c2, k-quarter q)
    float cp = 0.f;
    #pragma unroll
    for (int i = 0; i < 16; i++){
      const uint4 wr = wB[i];
      const uint4 rp = wv4[q*16 + i];
      cp = fdot2_(wr.x, rp.x, cp);
      cp = fdot2_(wr.y, rp.y, cp);
      cp = fdot2_(wr.z, rp.z, cp);
      cp = fdot2_(wr.w, rp.w, cp);
    }
    ph[tid] = cp;
    __syncthreads();                                   // bar6
    float cel = 0.f, hj = 0.f;
    if (isZ){
      cel = mu * (ph[tid] + ph[tid+128] + ph[tid+256] + ph[tid+384]);
      hj  = hf[jg];
    }
    // ---- S3: 8 candidate dots
    {
      float v[8] = { cel*cel, cel*yc, yc*yc, cel*bcj, yc*bcj, hj*cel, hj*yc, hj*bcj };
      wave_reduce_store<8>(v, red, tid);
    }
    __syncthreads();                                   // bar7
    if (wave == 0 && lane < 8){
      float s = 0.f;
      const float* r = red + lane*8;
      #pragma unroll
      for (int i = 0; i < 8; i++) s += r[i];
      postf(s3Row + w*16 + lane, s, tag);
    }
    if (wave == 0){
      const int wgi = lane >> 4, s = lane & 15;
      float v = (s < 8) ? pollf(s3Row + wgi*16 + s, tag) : 0.f;
      v += __shfl_xor(v, 16);
      v += __shfl_xor(v, 32);
      if (lane < 16) xr[lane] = v;
    }
    __syncthreads();                                   // bar8
    const float C2 = xr[0], CY = xr[1], Y2c = xr[2], CB = xr[3],
                YBc = xr[4], HC = xr[5], HYd = xr[6], HBd = xr[7];
    const float craw = sqrtf(C2);
    const float cmn2 = fmaxf(craw, EPSF);
    const float alc = (craw <= EPSF) ? 0.f : (tanhf(cmn2/rhn*artanh_c(rhn))/cmn2);
    const float X2c = alc*alc*C2, XYc = alc*CY, XBc = alc*CB, HXc = alc*HC;
    const float cA1c = 1.f + 2.f*XYc + Y2c, cB1c = 1.f - X2c;
    const float den1c = fmaxf(1.f + 2.f*XYc + X2c*Y2c, EPSF), id1c = 1.f/den1c;
    const float T2c = fmaxf((cA1c*cA1c*X2c + 2.f*cA1c*cB1c*XYc + cB1c*cB1c*Y2c)*id1c*id1c, 0.f);
    const float TBc = (cA1c*XBc + cB1c*YBc)*id1c;
    const float HT1 = (cA1c*HXc + cB1c*HYd)*id1c;
    const float cA2c = 1.f + 2.f*TBc + BC2, cB2c = 1.f - T2c;
    const float den2c = fmaxf(1.f + 2.f*TBc + T2c*BC2, EPSF), id2c = 1.f/den2c;
    const float HTL2 = fmaxf((cA2c*cA2c*T2c + 2.f*cA2c*cB2c*TBc + cB2c*cB2c*BC2)*id2c*id2c, 0.f);
    const float HHTL = (cA2c*HT1 + cB2c*HBd)*id2c;
    const float cAd = 1.f - 2.f*HHTL + HTL2, cBd = 1.f - H2;
    const float dend = fmaxf(1.f - 2.f*HHTL + H2*HTL2, EPSF), idd = 1.f/dend;
    float del = 0.f, w2el = 0.f;
    if (isZ){
      const float t1cel = (cA1c*(alc*cel) + cB1c*yc)*id1c;
      const float htlel = (cA2c*t1cel + cB2c*bcj)*id2c;
      del = (cAd*(-hj) + cBd*htlel)*idd;
      w2el = zreg*del;
    }
    // ---- S4: {d2, |z.*d|2, h.(z.*d)}
    {
      float v[3] = { del*del, w2el*w2el, hj*w2el };
      wave_reduce_store<3>(v, red, tid);
    }
    __syncthreads();                                   // bar9
    if (wave == 0 && lane < 3){
      float s = 0.f;
      const float* r = red + lane*8;
      #pragma unroll
      for (int i = 0; i < 8; i++) s += r[i];
      postf(s4Row + w*16 + lane, s, tag);
    }
    if (wave == 0){
      const int wgi = lane >> 4, s = lane & 15;
      float v = (s < 3) ? pollf(s4Row + wgi*16 + s, tag) : 0.f;
      v += __shfl_xor(v, 16);
      v += __shfl_xor(v, 32);
      if (lane < 16) xr[lane] = v;
    }
    __syncthreads();                                   // bar10
    const float D2v = xr[0], W22 = xr[1], HW = xr[2];
    const float dnv = fmaxf(sqrtf(D2v), EPSF);
    const float w2raw = sqrtf(W22);
    const float w2n = fmaxf(w2raw, EPSF);
    const float nu = (w2raw <= EPSF) ? 0.f : (tanhf(w2n/dnv*artanh_c(dnv))/w2n);
    const float Y2f = nu*nu*W22, XYf = nu*HW;
    const float cAf = 1.f + 2.f*XYf + Y2f, cBf = 1.f - H2;
    const float denf = fmaxf(1.f + 2.f*XYf + H2*Y2f, EPSF), idf = 1.f/denf;
    if (isZ){
      const float hnew = (cAf*hj + cBf*(nu*w2el))*idf;
      outbuf[(size_t)(t*B_ + b)*H_ + jg] = hnew;
      postf(hRow + jg, hnew, tag);         // tag t+1, polled by step t+1
      if (t == T_-1) hlast[b*H_ + jg] = hnew;
    }
  }
}

extern "C" void kernel_launch(void* const* d_in, const int* in_sizes, int n_in,
                              void* d_out, int out_size, void* d_ws, size_t ws_size,
                              hipStream_t stream){
  (void)in_sizes; (void)n_in; (void)out_size; (void)ws_size;
  const float* input = (const float*)d_in[0];
  const float* h0    = (const float*)d_in[1];
  const float* wih1  = (const float*)d_in[2];
  const float* wih2  = (const float*)d_in[3];
  const float* whh1  = (const float*)d_in[4];
  const float* whh2  = (const float*)d_in[5];
  const float* bias1 = (const float*)d_in[6];
  const float* bias2 = (const float*)d_in[7];
  float* out = (float*)d_out;

  // ws (floats): WihT 786432 | Dbuf 25165824 | WzrR 262144 | WhcR 131072
  //              per-layer comm x2: hS 65536 | wvS 65536 | S1 8192 | S3 8192 | S4 8192
  float* A_    = (float*)d_ws;
  float* Dbuf  = A_ + 786432;
  uint4* WzrR  = (uint4*)(Dbuf + 25165824);
  uint4* WhcR  = WzrR + 65536;
  float* comm0 = (float*)(WhcR + 32768);
  unsigned long long* hS1  = (unsigned long long*)comm0;
  unsigned long long* wvS1 = hS1  + 32768;
  unsigned long long* S1a  = wvS1 + 32768;
  unsigned long long* S3a  = S1a  + 4096;
  unsigned long long* S4a  = S3a  + 4096;
  unsigned long long* hS2  = S4a  + 4096;
  unsigned long long* wvS2 = hS2  + 32768;
  unsigned long long* S1b  = wvS2 + 32768;
  unsigned long long* S3b  = S1b  + 4096;
  unsigned long long* S4b  = S3b  + 4096;

  float* out1 = out;                          // staged; consumed before scan-2 overwrites
  float* ht   = out + (size_t)T_ * B_ * H_;

  // layer 1
  k_prep_ih<<<3072, 256, 0, stream>>>(wih1, A_);
  k_gemm<<<dim3(256, 24), 256, 0, stream>>>(input, A_, Dbuf);
  k_nonlin<<<T_*B_, 64, 0, stream>>>(input, Dbuf);
  k_prep_hhR<<<384, 256, 0, stream>>>(whh1, WzrR, WhcR);
  k_scan<<<256, 512, 0, stream>>>(Dbuf, WzrR, WhcR, bias1, h0, out1, ht,
                                  hS1, wvS1, S1a, S3a, S4a);

  // layer 2
  k_prep_ih<<<3072, 256, 0, stream>>>(wih2, A_);
  k_gemm<<<dim3(256, 24), 256, 0, stream>>>(out1, A_, Dbuf);
  k_nonlin<<<T_*B_, 64, 0, stream>>>(out1, Dbuf);
  k_prep_hhR<<<384, 256, 0, stream>>>(whh2, WzrR, WhcR);
  k_scan<<<256, 512, 0, stream>>>(Dbuf, WzrR, WhcR, bias2, h0 + B_*H_, out, ht + B_*H_,
                                  hS2, wvS2, S1b, S3b, S4b);
}